// Round 3
// baseline (499.079 us; speedup 1.0000x reference)
//
#include <hip/hip_runtime.h>
#include <hip/hip_bf16.h>

// ModulatedConv (StyleGAN2 conv_transpose2d stride=2, K=3) on gfx950.
// Round 3: barrier-free streaming GEMM. No LDS in the conv kernel: A (wT rows)
// and B (xmp sites) fragments load global->VGPR as 16B/lane (16 full 64B lines
// per inst), compiler interleaves MFMA with loads via fine-grained vmcnt.
// Blocks merge the two x-phases (px=0,1) of one y-phase py -> float2 dense
// output stores. Tap (ky,kx): out y=2u+py needs ky=py+2*dh (dh in {0,1}),
// x=2v+px needs kx with px=kx&1, dw=kx>>1; B variant = xmp[u-dh][v-dw].

typedef __attribute__((ext_vector_type(8))) short short8;
typedef __attribute__((ext_vector_type(4))) float floatx4;

#define CIN   512
#define COUT  512
#define OW    65
#define NSITE 1089     // 33*33 sites (u,v)

// ---- prep kernels (unchanged from round 2, all validated) --------------

__global__ void k_s(const float* __restrict__ w, const float* __restrict__ lin_w,
                    const float* __restrict__ lin_b, float* __restrict__ s)
{
    int i = blockIdx.x * 256 + threadIdx.x;
    int b = blockIdx.y;
    const float* wr = w + b * 512;
    const float* lr = lin_w + (size_t)i * 512;
    float acc = 0.f;
    for (int d = 0; d < 512; d += 4) {
        float4 a = *(const float4*)(wr + d);
        float4 c = *(const float4*)(lr + d);
        acc += a.x*c.x + a.y*c.y + a.z*c.z + a.w*c.w;
    }
    s[b * 512 + i] = acc * 0.0625f + lin_b[i];
}

__global__ void k_wq(const float* __restrict__ weight,
                     __hip_bfloat16* __restrict__ wT, float* __restrict__ q)
{
    int idx = blockIdx.x * 256 + threadIdx.x;   // o*512+i
    const float* p = weight + (size_t)idx * 9;
    float v[9], acc = 0.f;
#pragma unroll
    for (int j = 0; j < 9; ++j) { v[j] = p[j]; acc += v[j] * v[j]; }
    q[idx] = acc;
#pragma unroll
    for (int t = 0; t < 9; ++t)
        wT[t * 262144 + idx] = __float2bfloat16(v[t] * (1.0f / 48.0f));
}

__global__ void k_inv(const float* __restrict__ s, const float* __restrict__ q,
                      float* __restrict__ inv)
{
    int idx = blockIdx.x * 256 + threadIdx.x;   // b*512+o
    int b = idx >> 9;
    int o = idx & 511;
    const float* sp = s + b * 512;
    const float* qp = q + (size_t)o * 512;
    float acc = 0.f;
    for (int i = 0; i < 512; i += 4) {
        float4 sv = *(const float4*)(sp + i);
        float4 qv = *(const float4*)(qp + i);
        acc += sv.x*sv.x*qv.x + sv.y*sv.y*qv.y + sv.z*sv.z*qv.z + sv.w*sv.w*qv.w;
    }
    inv[idx] = 1.0f / sqrtf(acc * (1.0f / 2304.0f) + 1e-8f);
}

__global__ void k_zero(__hip_bfloat16* __restrict__ xmp)
{
    int idx = blockIdx.x * 256 + threadIdx.x;   // < 16*132*64
    int kc = idx & 63;
    int j  = (idx >> 6) % 132;
    int b  = (idx >> 6) / 132;
    int r, c;
    if (j < 34)       { r = 0;           c = j; }
    else if (j < 68)  { r = 33;          c = j - 34; }
    else if (j < 100) { r = j - 68 + 1;  c = 0; }
    else              { r = j - 100 + 1; c = 33; }
    uint4 z = {0u, 0u, 0u, 0u};
    *(uint4*)(xmp + (((size_t)b * 34 + r) * 34 + c) * 512 + kc * 8) = z;
}

__global__ void k_xprep(const float* __restrict__ x, const float* __restrict__ s,
                        __hip_bfloat16* __restrict__ xmp)
{
    __shared__ float tile[32][33];
    int i0 = blockIdx.x * 32;
    int h  = blockIdx.y;
    int b  = blockIdx.z;
    int tw = threadIdx.x & 31;
    int ti = threadIdx.x >> 5;
#pragma unroll
    for (int r = 0; r < 4; ++r) {
        int il = ti + r * 8;
        int i  = i0 + il;
        tile[il][tw] = x[(((size_t)b * 512 + i) * 32 + h) * 32 + tw] * s[b * 512 + i];
    }
    __syncthreads();
#pragma unroll
    for (int r = 0; r < 4; ++r) {
        int wc = ti + r * 8;
        xmp[(((size_t)b * 34 + h + 1) * 34 + (wc + 1)) * 512 + i0 + tw] =
            __float2bfloat16(tile[tw][wc]);
    }
}

// ---- main conv kernel: barrier-free, LDS-free --------------------------
// grid (9 site_tiles, py*4+o_tile (py=0 heavy first), 16 b), 256 thr = 4 waves.
// Block: M=128 o x N=128 sites, both px phases. Wave (wm,wn) = 64x64 quadrant.

template <int PY>
__device__ __forceinline__ void conv_body(
    const __hip_bfloat16* __restrict__ wT,
    const __hip_bfloat16* __restrict__ xmp,
    const float* __restrict__ inv,
    float* __restrict__ out)
{
    constexpr int NDH = (PY == 0) ? 2 : 1;

    const int tid  = threadIdx.x;
    const int lane = tid & 63;
    const int wv   = tid >> 6;
    const int wm   = wv & 1;
    const int wn   = wv >> 1;
    const int quad = lane >> 4;
    const int c16  = lane & 15;

    const int site_tile = blockIdx.x;
    const int o_tile    = blockIdx.y & 3;
    const int b         = blockIdx.z;
    const int s0        = site_tile * 128;
    const int u_base    = s0 / 33;
    const int o_base    = o_tile * 128;

    // A-frag lane offsets (bf16 elements): row = o local, k = quad*8
    int aoff[4];
#pragma unroll
    for (int a = 0; a < 4; ++a)
        aoff[a] = (wm * 64 + a * 16 + c16) * CIN + quad * 8;

    // B-frag lane offsets relative to padded base (row u_base+1, col 1):
    // (du*34 + v)*512 + quad*8 ; dh via -34*512, dw via -512 (both applied later)
    int boff[4];
#pragma unroll
    for (int f = 0; f < 4; ++f) {
        int site = s0 + wn * 64 + f * 16 + c16;
        if (site > 1088) site = 1088;          // clamp tail (epilogue skips them)
        int u = site / 33;
        int v = site - u * 33;
        boff[f] = ((u - u_base) * 34 + v) * CIN + quad * 8;
    }

    const __hip_bfloat16* xb0 =
        xmp + (((size_t)b * 34 + (u_base + 1)) * 34 + 1) * CIN;

    floatx4 acc[2][4][4];
#pragma unroll
    for (int p = 0; p < 2; ++p)
#pragma unroll
        for (int a = 0; a < 4; ++a)
#pragma unroll
            for (int f = 0; f < 4; ++f)
                acc[p][a][f] = (floatx4){0.f, 0.f, 0.f, 0.f};

    for (int kc = 0; kc < 16; ++kc) {
        const int k0 = kc * 32;
#pragma unroll
        for (int g = 0; g < NDH; ++g) {
            const __hip_bfloat16* xb = xb0 + k0 - g * (34 * CIN);
            short8 B[4][2];
#pragma unroll
            for (int f = 0; f < 4; ++f) {
                B[f][0] = *(const short8*)(xb + boff[f]);
                B[f][1] = *(const short8*)(xb + boff[f] - CIN);
            }
            const int ky = PY + 2 * g;
#pragma unroll
            for (int kx = 0; kx < 3; ++kx) {
                const __hip_bfloat16* wb =
                    wT + ((size_t)(ky * 3 + kx) * COUT + o_base) * CIN + k0;
                short8 A[4];
#pragma unroll
                for (int a = 0; a < 4; ++a)
                    A[a] = *(const short8*)(wb + aoff[a]);
                // px = kx&1, B variant dw = kx>>1
#pragma unroll
                for (int f = 0; f < 4; ++f)
#pragma unroll
                    for (int a = 0; a < 4; ++a)
                        acc[kx & 1][a][f] = __builtin_amdgcn_mfma_f32_16x16x32_bf16(
                            A[a], B[f][kx >> 1], acc[kx & 1][a][f], 0, 0, 0);
            }
        }
    }

    // epilogue: D col(c16)->site, row(quad*4+reg)->o. x pair (2v, 2v+1).
#pragma unroll
    for (int a = 0; a < 4; ++a) {
        const int oa = o_base + wm * 64 + a * 16 + quad * 4;
        float iv[4];
#pragma unroll
        for (int r = 0; r < 4; ++r) iv[r] = inv[b * COUT + oa + r];
#pragma unroll
        for (int f = 0; f < 4; ++f) {
            int site = s0 + wn * 64 + f * 16 + c16;
            if (site < NSITE) {
                int u = site / 33;
                int v = site - u * 33;
                int y = 2 * u + PY;
                if (y < OW) {
                    float* p0 = out + (((size_t)b * COUT + oa) * OW + y) * OW + 2 * v;
#pragma unroll
                    for (int r = 0; r < 4; ++r) {
                        float2 val;
                        val.x = acc[0][a][f][r] * iv[r];
                        val.y = acc[1][a][f][r] * iv[r];
                        float* p = p0 + (size_t)r * (OW * OW);
                        if (v < 32) *(float2*)p = val;
                        else        *p = val.x;
                    }
                }
            }
        }
    }
}

__global__ __launch_bounds__(256, 2)
void conv_main(const __hip_bfloat16* __restrict__ wT,
               const __hip_bfloat16* __restrict__ xmp,
               const float* __restrict__ inv,
               float* __restrict__ out)
{
    if ((blockIdx.y >> 2) == 0) conv_body<0>(wT, xmp, inv, out);
    else                        conv_body<1>(wT, xmp, inv, out);
}

// ---- launcher ----------------------------------------------------------
extern "C" void kernel_launch(void* const* d_in, const int* in_sizes, int n_in,
                              void* d_out, int out_size, void* d_ws, size_t ws_size,
                              hipStream_t stream)
{
    const float* x      = (const float*)d_in[0];   // (16,512,32,32)
    const float* w      = (const float*)d_in[1];   // (16,512)
    const float* weight = (const float*)d_in[2];   // (1,512,512,3,3)
    const float* lin_w  = (const float*)d_in[3];   // (512,512)
    const float* lin_b  = (const float*)d_in[4];   // (512,)
    float* out = (float*)d_out;                    // (16,512,65,65)

    char* ws = (char*)d_ws;
    float* s_buf   = (float*)(ws);                         //   32 KB
    float* inv_buf = (float*)(ws + 32768);                 //   32 KB
    float* q_buf   = (float*)(ws + 65536);                 //    1 MB
    __hip_bfloat16* wT  = (__hip_bfloat16*)(ws + 1114112); // 4.72 MB [9][512][512]
    __hip_bfloat16* xmp = (__hip_bfloat16*)(ws + 5832704); // 18.9 MB [16][34][34][512]

    k_s    <<<dim3(2, 16),      256, 0, stream>>>(w, lin_w, lin_b, s_buf);
    k_wq   <<<1024,             256, 0, stream>>>(weight, wT, q_buf);
    k_zero <<<528,              256, 0, stream>>>(xmp);
    k_inv  <<<32,               256, 0, stream>>>(s_buf, q_buf, inv_buf);
    k_xprep<<<dim3(16, 32, 16), 256, 0, stream>>>(x, s_buf, xmp);
    conv_main<<<dim3(9, 8, 16), 256, 0, stream>>>(wT, xmp, inv_buf, out);
}